// Round 1
// baseline (269.855 us; speedup 1.0000x reference)
//
#include <hip/hip_runtime.h>

#define IN_C 64
#define OUT_C 128
#define HID 32
#define KNB 16

__device__ __forceinline__ float leaky(float v, float s) { return v >= 0.f ? v : s * v; }

// Kernel 1: h = leaky(x @ W_in + b_in, 0.1)   [P,64] -> [P,32]
__global__ __launch_bounds__(256) void hid_kernel(
    const float* __restrict__ x, const float* __restrict__ Win,
    const float* __restrict__ bin, float* __restrict__ h, int total)
{
    int i = blockIdx.x * blockDim.x + threadIdx.x;
    if (i >= total) return;
    int p = i >> 5;        // point
    int c = i & 31;        // hidden channel
    float acc = bin[c];
    const float* xr = x + (long)p * IN_C;
    #pragma unroll
    for (int k = 0; k < IN_C; ++k) acc = fmaf(xr[k], Win[k * HID + c], acc);
    h[i] = leaky(acc, 0.1f);
}

// Kernel 2: per-point edge MLP + conv + output GEMV + residual + final leaky
__global__ __launch_bounds__(256) void point_kernel(
    const float* __restrict__ x, const float* __restrict__ pos,
    const int* __restrict__ nbr, const float* __restrict__ h,
    const float* __restrict__ Wa, const float* __restrict__ ba,
    const float* __restrict__ Wb, const float* __restrict__ bb,
    const float* __restrict__ Wout, const float* __restrict__ bout,
    const float* __restrict__ Wsc, const float* __restrict__ bsc,
    float* __restrict__ out, int N, int P)
{
    int p = blockIdx.x * blockDim.x + threadIdx.x;
    if (p >= P) return;
    long pbase = (long)(p / N) * N;   // batch base row (idx is per-batch)

    float px = pos[(long)p * 3 + 0];
    float py = pos[(long)p * 3 + 1];
    float pz = pos[(long)p * 3 + 2];

    // x row in registers (for shortcut GEMV)
    float xr[IN_C];
    {
        const float4* x4 = (const float4*)(x + (long)p * IN_C);
        #pragma unroll
        for (int i2 = 0; i2 < IN_C / 4; ++i2) {
            float4 v = x4[i2];
            xr[4 * i2 + 0] = v.x; xr[4 * i2 + 1] = v.y;
            xr[4 * i2 + 2] = v.z; xr[4 * i2 + 3] = v.w;
        }
    }

    float conv[HID];
    #pragma unroll
    for (int c = 0; c < HID; ++c) conv[c] = 0.f;

    #pragma unroll 1
    for (int e = 0; e < KNB; ++e) {
        int j = nbr[(long)p * KNB + e];
        long q = pbase + j;
        float rx = px - pos[q * 3 + 0];
        float ry = py - pos[q * 3 + 1];
        float rz = pz - pos[q * 3 + 2];

        // gathered h row
        float hg[HID];
        {
            const float4* h4 = (const float4*)(h + q * HID);
            #pragma unroll
            for (int i2 = 0; i2 < HID / 4; ++i2) {
                float4 v = h4[i2];
                hg[4 * i2 + 0] = v.x; hg[4 * i2 + 1] = v.y;
                hg[4 * i2 + 2] = v.z; hg[4 * i2 + 3] = v.w;
            }
        }

        // t = leaky(rel @ Wa + ba, 0.1)
        float t[HID];
        #pragma unroll
        for (int c = 0; c < HID; ++c) {
            float v = fmaf(rx, Wa[c], fmaf(ry, Wa[HID + c], fmaf(rz, Wa[2 * HID + c], ba[c])));
            t[c] = leaky(v, 0.1f);
        }

        // w = t @ Wb + bb ; conv += w * hg
        #pragma unroll
        for (int c = 0; c < HID; ++c) {
            float wv = bb[c];
            #pragma unroll
            for (int jj = 0; jj < HID; ++jj) wv = fmaf(t[jj], Wb[jj * HID + c], wv);
            conv[c] = fmaf(wv, hg[c], conv[c]);
        }
    }

    // out = leaky(conv @ Wout + bout + x @ Wsc + bsc, 0.01)
    float* op = out + (long)p * OUT_C;
    #pragma unroll 1
    for (int o = 0; o < OUT_C; o += 4) {
        float a[4];
        #pragma unroll
        for (int l = 0; l < 4; ++l) a[l] = bout[o + l] + bsc[o + l];
        #pragma unroll
        for (int c = 0; c < HID; ++c) {
            float cv = conv[c];
            const float* wrow = Wout + c * OUT_C + o;
            #pragma unroll
            for (int l = 0; l < 4; ++l) a[l] = fmaf(cv, wrow[l], a[l]);
        }
        #pragma unroll
        for (int k = 0; k < IN_C; ++k) {
            float xv = xr[k];
            const float* wrow = Wsc + k * OUT_C + o;
            #pragma unroll
            for (int l = 0; l < 4; ++l) a[l] = fmaf(xv, wrow[l], a[l]);
        }
        float4 vo;
        vo.x = leaky(a[0], 0.01f);
        vo.y = leaky(a[1], 0.01f);
        vo.z = leaky(a[2], 0.01f);
        vo.w = leaky(a[3], 0.01f);
        *(float4*)(op + o) = vo;
    }
}

extern "C" void kernel_launch(void* const* d_in, const int* in_sizes, int n_in,
                              void* d_out, int out_size, void* d_ws, size_t ws_size,
                              hipStream_t stream) {
    const float* x    = (const float*)d_in[0];
    const float* pos  = (const float*)d_in[1];
    const int*   nbr  = (const int*)d_in[2];
    const float* Win  = (const float*)d_in[3];
    const float* bin  = (const float*)d_in[4];
    const float* Wa   = (const float*)d_in[5];
    const float* ba   = (const float*)d_in[6];
    const float* Wb   = (const float*)d_in[7];
    const float* bb   = (const float*)d_in[8];
    const float* Wout = (const float*)d_in[9];
    const float* bout = (const float*)d_in[10];
    const float* Wsc  = (const float*)d_in[11];
    const float* bsc  = (const float*)d_in[12];
    float* out = (float*)d_out;

    int P = in_sizes[0] / IN_C;   // B*N = 131072
    int N = P / 2;                // B = 2 per reference
    float* h = (float*)d_ws;      // P*HID floats = 16.8 MB

    int total = P * HID;
    hid_kernel<<<(total + 255) / 256, 256, 0, stream>>>(x, Win, bin, h, total);
    point_kernel<<<(P + 255) / 256, 256, 0, stream>>>(
        x, pos, nbr, h, Wa, ba, Wb, bb, Wout, bout, Wsc, bsc, out, N, P);
}